// Round 8
// baseline (108.271 us; speedup 1.0000x reference)
//
#include <hip/hip_runtime.h>

// Receptive-field spike encoder:
//   out[t, b, d] = ( clip( (int)(scaling[d] * |x[b] - center[d]|), 0, T-1 ) == t ) ? 1 : 0
// Output [T, B, N=16] float32, 512 MiB -> write-BW-bound.
//
// Round-8: refined round-6 (proven correct, 107 us). Ownership unchanged:
// block = one contiguous 64 KiB chunk of the flat output (8192 blocks march
// linearly), lane i stores 16B at base + i*16 (1 KiB per wave-instruction),
// nontemporal stores. Refinements:
//   - t is block-uniform (a 64 KiB chunk = 1024 rows never straddles a
//     t-plane since B % 1024 == 0) -> hoisted to a scalar.
//   - each WAVE owns a contiguous 16 KiB run (its 16 stores march linearly
//     1 KiB apart) instead of 4 KiB-strided interleave.
//   - the 16 x-values per thread are preloaded into registers up-front.
//   - __launch_bounds__(256) + lean index math -> <=64 VGPR, 8 blocks/CU.

typedef float f32x4 __attribute__((ext_vector_type(4)));

#define ITERS 16  // 16B chunks per thread; block = 256 thr * 16 * 16B = 64 KiB

__global__ void __launch_bounds__(256)
rf_encode_lin(const float* __restrict__ x,
              const float* __restrict__ center,
              const float* __restrict__ scaling,
              float* __restrict__ out,
              int logB, int Bmask, int T) {
    const int lane = threadIdx.x & 63;
    const int wave = threadIdx.x >> 6;
    const int qt   = lane & 3;   // which 4 of the 16 receptive fields

    // block owns 64 KiB = 4096 chunks = 1024 rows, all within ONE t-plane
    const long long blockRow0 = (long long)blockIdx.x << 10;   // * 1024 rows
    const int t       = (int)(blockRow0 >> logB);              // block-uniform
    const int rowBase = (int)(blockRow0 & Bmask);              // first b of block

    // this thread's row at iteration 0; advances 16 rows per iteration
    const int myRow0 = rowBase + wave * 256 + (lane >> 2);

    // preload the 16 x-values (per wave-iter: 16 consecutive floats, L1-served)
    float xv[ITERS];
    #pragma unroll
    for (int it = 0; it < ITERS; ++it)
        xv[it] = x[myRow0 + it * 16];

    const f32x4 c4 = reinterpret_cast<const f32x4*>(center)[qt];
    const f32x4 s4 = reinterpret_cast<const f32x4*>(scaling)[qt];

    // wave owns a contiguous 16 KiB run: chunk = blk*4096 + wave*1024 + it*64 + lane
    f32x4* o = reinterpret_cast<f32x4*>(out)
             + (((long long)blockIdx.x << 12) + (wave << 10) + lane);

    #pragma unroll
    for (int it = 0; it < ITERS; ++it) {
        const float xb = xv[it];
        // exact numpy op sequence: sub, abs, mul, trunc-to-int32, clip
        int v0 = (int)(s4.x * fabsf(xb - c4.x)); v0 = min(max(v0, 0), T - 1);
        int v1 = (int)(s4.y * fabsf(xb - c4.y)); v1 = min(max(v1, 0), T - 1);
        int v2 = (int)(s4.z * fabsf(xb - c4.z)); v2 = min(max(v2, 0), T - 1);
        int v3 = (int)(s4.w * fabsf(xb - c4.w)); v3 = min(max(v3, 0), T - 1);
        f32x4 r;
        r.x = (v0 == t) ? 1.0f : 0.0f;
        r.y = (v1 == t) ? 1.0f : 0.0f;
        r.z = (v2 == t) ? 1.0f : 0.0f;
        r.w = (v3 == t) ? 1.0f : 0.0f;
        __builtin_nontemporal_store(r, o + it * 64);
    }
}

// generic fallback (N != 16, B not pow2, or B % 1024 != 0)
__global__ void rf_encode_generic(const float* __restrict__ x,
                                  const float* __restrict__ center,
                                  const float* __restrict__ scaling,
                                  float* __restrict__ out,
                                  int B, int N, int T) {
    long long tid = (long long)blockIdx.x * blockDim.x + threadIdx.x;
    long long total = (long long)T * B;
    if (tid >= total) return;
    int b = (int)(tid % B);
    int t = (int)(tid / B);
    float xb = x[b];
    float* o = out + ((long long)t * B + (long long)b) * N;
    for (int d = 0; d < N; ++d) {
        float dist = fabsf(xb - center[d]);
        int v = (int)(scaling[d] * dist);
        v = min(max(v, 0), T - 1);
        o[d] = (v == t) ? 1.0f : 0.0f;
    }
}

extern "C" void kernel_launch(void* const* d_in, const int* in_sizes, int n_in,
                              void* d_out, int out_size, void* d_ws, size_t ws_size,
                              hipStream_t stream) {
    const float* x       = (const float*)d_in[0];
    const float* center  = (const float*)d_in[1];
    const float* scaling = (const float*)d_in[2];
    float* out = (float*)d_out;

    int B = in_sizes[0];
    int N = in_sizes[1];
    int T = (int)((long long)out_size / ((long long)B * (long long)N));

    bool bpow2 = (B & (B - 1)) == 0;
    if (N == 16 && bpow2 && (B % 1024) == 0) {
        int logB = 0;
        while ((1 << logB) < B) ++logB;
        // one block per 1024 rows; rows total = T*B (divisible by 1024)
        long long rows = (long long)T * B;
        int nblocks = (int)(rows >> 10);
        rf_encode_lin<<<nblocks, 256, 0, stream>>>(x, center, scaling, out,
                                                   logB, B - 1, T);
    } else {
        long long total = (long long)T * B;
        const int block = 256;
        int blocks = (int)((total + block - 1) / block);
        rf_encode_generic<<<blocks, block, 0, stream>>>(x, center, scaling, out, B, N, T);
    }
}

// Round 9
// 100.475 us; speedup vs baseline: 1.0776x; 1.0776x over previous
//
#include <hip/hip_runtime.h>

// Receptive-field spike encoder:
//   out[t, b, d] = ( clip( (int)(scaling[d] * |x[b] - center[d]|), 0, T-1 ) == t ) ? 1 : 0
// Output [T, B, N=16] float32, 512 MiB -> write-BW-bound.
//
// Round-9: longer-lived blocks (fillBuffer-shaped grid). Identical per-64KiB
// body to round 8 (proven, 108 us), but 2048 blocks x contiguous 256 KiB
// chunks instead of 8192 x 64 KiB: 4x fewer block launch/drain cycles per CU,
// amortizing CP dispatch ramp and per-block cold-start. fillBuffer (6.86 TB/s
// on this chip) runs exactly this persistent small-grid shape (Occupancy
// ~10%, VGPR 8). Store path unchanged: nt dwordx4, lane i at base + i*16
// (1 KiB per wave-instruction), wave owns contiguous 16 KiB runs.

typedef float f32x4 __attribute__((ext_vector_type(4)));

#define SUBS  4   // 64 KiB sub-chunks per block -> 256 KiB per block
#define ITERS 16  // 16B chunks per thread per sub-chunk

__global__ void __launch_bounds__(256)
rf_encode_lin(const float* __restrict__ x,
              const float* __restrict__ center,
              const float* __restrict__ scaling,
              float* __restrict__ out,
              int logB, int Bmask, int T) {
    const int lane = threadIdx.x & 63;
    const int wave = threadIdx.x >> 6;
    const int qt   = lane & 3;   // which 4 of the 16 receptive fields

    const f32x4 c4 = reinterpret_cast<const f32x4*>(center)[qt];
    const f32x4 s4 = reinterpret_cast<const f32x4*>(scaling)[qt];

    // block owns 256 KiB = 4096 rows, all within ONE t-plane (B % 4096 == 0)
    const long long blockRow0 = (long long)blockIdx.x << 12;   // * 4096 rows
    const int t       = (int)(blockRow0 >> logB);              // block-uniform
    const int rowBase = (int)(blockRow0 & Bmask);              // first b of block

    for (int s = 0; s < SUBS; ++s) {
        // this sub-chunk: 64 KiB = 1024 rows
        const int subRow0 = rowBase + s * 1024 + wave * 256 + (lane >> 2);

        // preload the 16 x-values for this sub-chunk
        float xv[ITERS];
        #pragma unroll
        for (int it = 0; it < ITERS; ++it)
            xv[it] = x[subRow0 + it * 16];

        // wave owns a contiguous 16 KiB run within the sub-chunk
        f32x4* o = reinterpret_cast<f32x4*>(out)
                 + (((long long)blockIdx.x << 14) + (s << 12) + (wave << 10) + lane);

        #pragma unroll
        for (int it = 0; it < ITERS; ++it) {
            const float xb = xv[it];
            // exact numpy op sequence: sub, abs, mul, trunc-to-int32, clip
            int v0 = (int)(s4.x * fabsf(xb - c4.x)); v0 = min(max(v0, 0), T - 1);
            int v1 = (int)(s4.y * fabsf(xb - c4.y)); v1 = min(max(v1, 0), T - 1);
            int v2 = (int)(s4.z * fabsf(xb - c4.z)); v2 = min(max(v2, 0), T - 1);
            int v3 = (int)(s4.w * fabsf(xb - c4.w)); v3 = min(max(v3, 0), T - 1);
            f32x4 r;
            r.x = (v0 == t) ? 1.0f : 0.0f;
            r.y = (v1 == t) ? 1.0f : 0.0f;
            r.z = (v2 == t) ? 1.0f : 0.0f;
            r.w = (v3 == t) ? 1.0f : 0.0f;
            __builtin_nontemporal_store(r, o + it * 64);
        }
    }
}

// generic fallback (N != 16, B not pow2, or rows not divisible by 4096)
__global__ void rf_encode_generic(const float* __restrict__ x,
                                  const float* __restrict__ center,
                                  const float* __restrict__ scaling,
                                  float* __restrict__ out,
                                  int B, int N, int T) {
    long long tid = (long long)blockIdx.x * blockDim.x + threadIdx.x;
    long long total = (long long)T * B;
    if (tid >= total) return;
    int b = (int)(tid % B);
    int t = (int)(tid / B);
    float xb = x[b];
    float* o = out + ((long long)t * B + (long long)b) * N;
    for (int d = 0; d < N; ++d) {
        float dist = fabsf(xb - center[d]);
        int v = (int)(scaling[d] * dist);
        v = min(max(v, 0), T - 1);
        o[d] = (v == t) ? 1.0f : 0.0f;
    }
}

extern "C" void kernel_launch(void* const* d_in, const int* in_sizes, int n_in,
                              void* d_out, int out_size, void* d_ws, size_t ws_size,
                              hipStream_t stream) {
    const float* x       = (const float*)d_in[0];
    const float* center  = (const float*)d_in[1];
    const float* scaling = (const float*)d_in[2];
    float* out = (float*)d_out;

    int B = in_sizes[0];
    int N = in_sizes[1];
    int T = (int)((long long)out_size / ((long long)B * (long long)N));

    bool bpow2 = (B & (B - 1)) == 0;
    long long rows = (long long)T * B;
    if (N == 16 && bpow2 && (B % 4096) == 0 && (rows % 4096) == 0) {
        int logB = 0;
        while ((1 << logB) < B) ++logB;
        int nblocks = (int)(rows >> 12);   // 4096 rows (256 KiB) per block
        rf_encode_lin<<<nblocks, 256, 0, stream>>>(x, center, scaling, out,
                                                   logB, B - 1, T);
    } else {
        const int block = 256;
        int blocks = (int)((rows + block - 1) / block);
        rf_encode_generic<<<blocks, block, 0, stream>>>(x, center, scaling, out, B, N, T);
    }
}